// Round 3
// baseline (853.108 us; speedup 1.0000x reference)
//
#include <hip/hip_runtime.h>
#include <math.h>

#define AN 120000
#define NB 8
#define NC 80
#define MAXDET 100

typedef unsigned long long u64;
typedef unsigned int u32;

// identity pass-through that blocks FMA contraction / reassociation across it
__device__ __forceinline__ float opaquef(float x) { asm volatile("" : "+v"(x)); return x; }

// ---------------------------------------------------------------------------
// ctrl layout (u32 words at start of d_ws), zeroed by score_kernel every call:
//   [0..15]  prefix[8]  (u64[8])   radix-select running prefix per image
//   [16..23] need[8]               remaining count within prefix
//   [24..55] done[4][8]            tail-block counters per (level,image)
//   [56..63] gcnt[8]               compaction counters
//   [256..]  hist[4][8][4096] u32  per-level per-image histograms
#define CTRL_WORDS 256
#define HIST_WORDS (4 * 8 * 4096)
#define ZWORDS (CTRL_WORDS + HIST_WORDS)   // 131328 = 513 * 256

// ---------------------------------------------------------------------------
// Phase A: per-anchor max over 80 classes -> unique 48-bit sort key.
// key = (float_bits(score) << 17) | (131071 - anchor)
// ---------------------------------------------------------------------------
__global__ __launch_bounds__(256) void score_kernel(const float* __restrict__ cls,
                                                    u64* __restrict__ keys,
                                                    u32* __restrict__ ctrl) {
    if (blockIdx.x < 513) {
        ctrl[blockIdx.x * 256 + threadIdx.x] = 0;   // 513*256 == ZWORDS exactly
    }
    __shared__ float buf[4][32 * 81];
    const int tid = threadIdx.x;
    const int wave = tid >> 6, lane = tid & 63;
    const long long blockbase = (long long)blockIdx.x * 256;

    for (int h = 0; h < 2; ++h) {
        const long long abase = blockbase + wave * 64 + h * 32;
        const float4* src = (const float4*)(cls + abase * NC);
        float* Bf = buf[wave];
#pragma unroll
        for (int it = 0; it < 10; ++it) {
            int f = lane + it * 64;           // float4 index within 32x80 tile
            float4 v = src[f];                // fully coalesced
            int anch = f / 20, pos = (f % 20) * 4;
            float* dst = Bf + anch * 81 + pos;
            dst[0] = v.x; dst[1] = v.y; dst[2] = v.z; dst[3] = v.w;
        }
        __syncthreads();
        int anch = lane >> 1, half = lane & 1;   // 2 lanes per anchor
        const float* row = Bf + anch * 81 + half * 40;
        float best = -1.0f;
#pragma unroll
        for (int i = 0; i < 40; ++i) {
            float v = row[i];
            if (v > best) best = v;
        }
        float ov = __shfl_xor(best, 1);
        if (ov > best) best = ov;
        if (half == 0) {
            int aglob = (int)(abase + anch);
            int a = aglob % AN;
            keys[aglob] = ((u64)__float_as_uint(best) << 17) | (u64)(131071 - a);
        }
        __syncthreads();
    }
}

// ---------------------------------------------------------------------------
// Phase B: distributed exact radix select, level L of 4 (12-bit digits over the
// 48-bit key). 60 blocks per image build LDS histograms and flush non-zero bins
// to global; the per-image tail block picks the digit (suffix scan) and updates
// prefix/need. After L=3, prefix[img] == exact 1000th-largest key.
// ---------------------------------------------------------------------------
template <int L>
__global__ __launch_bounds__(256) void hist_kernel(const u64* __restrict__ keys,
                                                   u32* __restrict__ ctrl) {
    const int img = blockIdx.x / 60, chunk = blockIdx.x % 60;
    const int tid = threadIdx.x;
    u64* prefixp = (u64*)ctrl;
    u32* gh = ctrl + CTRL_WORDS + (L * 8 + img) * 4096;
    const u64* k = keys + (size_t)img * AN + chunk * 2000;

    __shared__ u32 h[4096];
    __shared__ u32 ss[256];
    __shared__ int s_last;
    for (int d = tid; d < 4096; d += 256) h[d] = 0;
    u64 pref = (L > 0) ? prefixp[img] : 0;
    __syncthreads();

    constexpr int shift = 36 - 12 * L;
    for (int i = tid; i < 2000; i += 256) {
        u64 K = k[i];
        if ((K >> (shift + 12)) == pref)
            atomicAdd(&h[(u32)(K >> shift) & 4095], 1u);
    }
    __syncthreads();
    for (int d = tid; d < 4096; d += 256)
        if (h[d]) atomicAdd(&gh[d], h[d]);
    __threadfence();
    __syncthreads();
    if (tid == 0) {
        u32 old = atomicAdd(&ctrl[24 + L * 8 + img], 1u);
        s_last = (old == 59u);
    }
    __syncthreads();
    if (!s_last) return;

    // ---- tail block: pick digit for this image ----
    const u32 need = (L == 0) ? 1000u : ctrl[16 + img];
    u32 b[16]; u32 S = 0;
#pragma unroll
    for (int j = 0; j < 16; ++j) {
        b[j] = __hip_atomic_load(&gh[tid * 16 + j], __ATOMIC_RELAXED, __HIP_MEMORY_SCOPE_AGENT);
        S += b[j];
    }
    ss[tid] = S;
    __syncthreads();
    for (int off = 1; off < 256; off <<= 1) {          // suffix scan across threads
        u32 v = (tid + off < 256) ? ss[tid + off] : 0;
        __syncthreads();
        ss[tid] += v;
        __syncthreads();
    }
    u32 run = ss[tid] - S;                              // count of digits in threads > tid
    for (int j = 15; j >= 0; --j) {                     // high digit -> low within thread
        u32 cge = run + b[j];
        if (cge >= need && run < need) {                // unique (tid,j)
            ctrl[16 + img] = need - run;
            prefixp[img] = (pref << 12) | (u64)(tid * 16 + j);
        }
        run = cge;
    }
}

// ---------------------------------------------------------------------------
// Phase C: compact — collect the exactly-1000 keys >= T per image (UNSORTED).
// ---------------------------------------------------------------------------
__global__ __launch_bounds__(256) void compact_kernel(const u64* __restrict__ keys,
                                                      u32* __restrict__ ctrl,
                                                      u64* __restrict__ topk) {
    const int img = blockIdx.x / 60, chunk = blockIdx.x % 60;
    const u64 T = ((const u64*)ctrl)[img];
    const u64* k = keys + (size_t)img * AN + chunk * 2000;
    for (int i = threadIdx.x; i < 2000; i += 256) {
        u64 K = k[i];
        if (K >= T) {
            u32 p = atomicAdd(&ctrl[56 + img], 1u);
            if (p < 1024) topk[img * 1024 + p] = K;
        }
    }
}

// ---------------------------------------------------------------------------
// Phase D: decode the selected (unsorted) candidates. No sort needed: NMS
// traverses by max-key. Class argmax recomputed for just the 8000 selected.
// ---------------------------------------------------------------------------
__global__ __launch_bounds__(256) void decode_kernel(const u64* __restrict__ topk,
                                                     const u32* __restrict__ ctrl,
                                                     const float* __restrict__ cls,
                                                     const float* __restrict__ reg,
                                                     const float* __restrict__ anch,
                                                     int* __restrict__ tcl,
                                                     float* __restrict__ tbox) {
    int t = blockIdx.x * 256 + threadIdx.x;
    int img = t >> 10, j = t & 1023;
    const u32 cnt = ctrl[56 + img];   // == 1000 (T exact, keys unique)
    if (j >= (int)cnt) return;

    u64 K = topk[t];
    int idx = 131071 - (int)(K & 0x1FFFF);
    size_t gi = (size_t)img * AN + idx;

    // class argmax (first occurrence)
    const float4* crow = (const float4*)(cls + gi * NC);
    float cb = -1.0f; int ci = 0;
#pragma unroll 5
    for (int c4 = 0; c4 < 20; ++c4) {
        float4 v = crow[c4];
        if (v.x > cb) { cb = v.x; ci = c4 * 4; }
        if (v.y > cb) { cb = v.y; ci = c4 * 4 + 1; }
        if (v.z > cb) { cb = v.z; ci = c4 * 4 + 2; }
        if (v.w > cb) { cb = v.w; ci = c4 * 4 + 3; }
    }

    float4 r = ((const float4*)reg)[gi];
    float4 a = ((const float4*)anch)[gi];
    float aw = a.z - a.x, ah = a.w - a.y;
    float acx = a.x + 0.5f * aw, acy = a.y + 0.5f * ah;
    float rx = opaquef(r.x * 0.1f), ry = opaquef(r.y * 0.1f);
    float rw = opaquef(r.z * 0.2f), rh = opaquef(r.w * 0.2f);
    float pw = opaquef((float)exp((double)rw) * aw);
    float ph = opaquef((float)exp((double)rh) * ah);
    float pcx = opaquef(rx * aw) + acx;
    float pcy = opaquef(ry * ah) + acy;
    float x1 = truncf(pcx - 0.5f * pw);
    float y1 = truncf(pcy - 0.5f * ph);
    float x2 = truncf(pcx + 0.5f * pw);
    float y2 = truncf(pcy + 0.5f * ph);
    x1 = fmaxf(x1, 0.0f); y1 = fmaxf(y1, 0.0f);
    x2 = fminf(x2, 639.0f); y2 = fminf(y2, 639.0f);

    tcl[t] = ci;
    ((float4*)tbox)[t] = make_float4(x1, y1, x2, y2);
}

// ---------------------------------------------------------------------------
// Phase E: single-wave greedy NMS per image. Lane l owns slots j = k*64+l
// (16 slots, registers). Next keeper = wave argmax of alive keys (desc-score
// order == desc-key order, keys unique, so the position test `j > i` in the
// reference is automatic). Zero __syncthreads. Early exit at 100 keeps.
// ---------------------------------------------------------------------------
__global__ __launch_bounds__(64) void nms_kernel(const u64* __restrict__ topk,
                                                 const u32* __restrict__ ctrl,
                                                 const int* __restrict__ tcl,
                                                 const float* __restrict__ tbox,
                                                 float* __restrict__ out) {
    const int img = blockIdx.x;
    const int lane = threadIdx.x;
    __shared__ float4 sbox[1024];
    __shared__ u64 skey[1024];
    __shared__ int keeplist[MAXDET];
    const u32 cnt = ctrl[56 + img];

    u64 mykey[16]; float4 mybox[16]; float marea[16];
    u32 alive = 0;
#pragma unroll
    for (int k = 0; k < 16; ++k) {
        int j = k * 64 + lane;
        u64 K = (j < (int)cnt) ? topk[img * 1024 + j] : 0ull;
        float4 b = ((const float4*)tbox)[img * 1024 + j];   // poison if j>=cnt (never used)
        mykey[k] = K; mybox[k] = b;
        marea[k] = (b.z - b.x) * (b.w - b.y);
        skey[j] = K; sbox[j] = b;
        if (__uint_as_float((u32)(K >> 17)) > 0.05f) alive |= (1u << k);
    }

    int kept = 0;
    for (;;) {
        // per-lane max over alive slots, then wave-wide max
        u64 best = 0; int bslot = -1;
#pragma unroll
        for (int k = 0; k < 16; ++k)
            if ((alive >> k) & 1u) { if (mykey[k] > best) { best = mykey[k]; bslot = k; } }
        u64 m = best;
#pragma unroll
        for (int off = 32; off > 0; off >>= 1) {
            u64 o = __shfl_xor(m, off);
            if (o > m) m = o;
        }
        if (m == 0) break;                       // none alive
        u64 who = __ballot(best == m);           // unique lane (keys unique)
        int owner = (int)__builtin_ctzll(who);
        int slot = __shfl(bslot, owner);
        int i = slot * 64 + owner;               // storage index of keeper
        if (lane == owner) alive &= ~(1u << slot);
        if (lane == 0) keeplist[kept] = i;
        kept++;
        if (kept >= MAXDET) break;               // first 100 keepers determine output
        float4 bi = sbox[i];                     // LDS broadcast (same address)
        float ai = (bi.z - bi.x) * (bi.w - bi.y);
#pragma unroll
        for (int k = 0; k < 16; ++k) {
            if ((alive >> k) & 1u) {
                float4 bj = mybox[k];
                float ltx = fmaxf(bi.x, bj.x), lty = fmaxf(bi.y, bj.y);
                float rbx = fminf(bi.z, bj.z), rby = fminf(bi.w, bj.w);
                float dx = fmaxf(rbx - ltx, 0.0f), dy = fmaxf(rby - lty, 0.0f);
                float inter = dx * dy;                   // exact int
                float uni = ai + marea[k] - inter;       // exact int
                if (inter / uni > 0.5f) alive &= ~(1u << k);   // IEEE div, bit-exact
            }
        }
    }

    const int n = kept;
    for (int s = lane; s < MAXDET; s += 64) {
        int o = img * MAXDET + s;
        if (s < n) {
            int i = keeplist[s];
            out[o] = __uint_as_float((u32)(skey[i] >> 17));     // exact score
            out[NB * MAXDET + o] = (float)tcl[img * 1024 + i];
            ((float4*)(out + 2 * NB * MAXDET))[o] = sbox[i];
        } else {
            out[o] = -1.0f;
            out[NB * MAXDET + o] = -1.0f;
            ((float4*)(out + 2 * NB * MAXDET))[o] = make_float4(-1.0f, -1.0f, -1.0f, -1.0f);
        }
    }
}

// ---------------------------------------------------------------------------
extern "C" void kernel_launch(void* const* d_in, const int* in_sizes, int n_in,
                              void* d_out, int out_size, void* d_ws, size_t ws_size,
                              hipStream_t stream) {
    const float* cls  = (const float*)d_in[0];
    const float* reg  = (const float*)d_in[1];
    const float* anch = (const float*)d_in[2];
    float* out = (float*)d_out;

    // workspace layout (~8.4 MB); all offsets 16B-aligned
    u32* ctrl = (u32*)d_ws;                                   // ZWORDS u32, zeroed by score_kernel
    u64* keys = (u64*)((char*)d_ws + (size_t)ZWORDS * 4);     // NB*AN u64
    u64* topk = keys + (size_t)NB * AN;                       // NB*1024 u64
    float* tbox = (float*)(topk + NB * 1024);                 // NB*1024*4 f32
    int*   tcl  = (int*)(tbox + NB * 1024 * 4);               // NB*1024 i32

    score_kernel<<<dim3(3750), dim3(256), 0, stream>>>(cls, keys, ctrl);
    hist_kernel<0><<<dim3(480), dim3(256), 0, stream>>>(keys, ctrl);
    hist_kernel<1><<<dim3(480), dim3(256), 0, stream>>>(keys, ctrl);
    hist_kernel<2><<<dim3(480), dim3(256), 0, stream>>>(keys, ctrl);
    hist_kernel<3><<<dim3(480), dim3(256), 0, stream>>>(keys, ctrl);
    compact_kernel<<<dim3(480), dim3(256), 0, stream>>>(keys, ctrl, topk);
    decode_kernel<<<dim3(32), dim3(256), 0, stream>>>(topk, ctrl, cls, reg, anch, tcl, tbox);
    nms_kernel<<<dim3(NB), dim3(64), 0, stream>>>(topk, ctrl, tcl, tbox, out);
}